// Round 1
// baseline (41571.338 us; speedup 1.0000x reference)
//
#include <hip/hip_runtime.h>

typedef _Float16 h2 __attribute__((ext_vector_type(2)));
typedef _Float16 h4 __attribute__((ext_vector_type(4)));
typedef _Float16 h8 __attribute__((ext_vector_type(8)));
union H8 { h8 v; h2 p[4]; };

#define AGENT __HIP_MEMORY_SCOPE_AGENT

__device__ __forceinline__ float dot2(h2 a, h2 b, float c) {
#if __has_builtin(__builtin_amdgcn_fdot2)
  return __builtin_amdgcn_fdot2(a, b, c, false);
#else
  return c + (float)a[0]*(float)b[0] + (float)a[1]*(float)b[1];
#endif
}
__device__ __forceinline__ float dot8(h8 x, h8 w, float acc) {
  H8 a, b; a.v = x; b.v = w;
  acc = dot2(a.p[0], b.p[0], acc); acc = dot2(a.p[1], b.p[1], acc);
  acc = dot2(a.p[2], b.p[2], acc); acc = dot2(a.p[3], b.p[3], acc);
  return acc;
}
__device__ __forceinline__ float sigm(float x){ return 1.f/(1.f+__expf(-x)); }

// ---------------- workspace layout (bytes) ----------------
// sync page @0 (gctr@0, grel@4, qctr@256), zeroed region covers state:
enum : unsigned long long {
  OFF_CA   = 4096ull,        // float[64*512]
  OFF_CB   = 135168ull,      // float[64*512]
  OFF_HA   = 266240ull,      // _Float16[2][64*512]
  OFF_HB   = 397312ull,      // _Float16[2][64*512]
  OFF_CTX  = 528384ull,      // _Float16[64*256]
  ZERO_W32 = 140288ull,      // words zeroed: 0 .. 561152
  OFF_PART = 561152ull,      // float[64][4][272]
  OFF_PEMB = 839680ull,      // float[34*2048]
  OFF_BB   = 1118208ull,     // float[2048]
  OFF_FLAG = 1126400ull,     // int
  OFF_WA   = 1126656ull,     // _Float16[2048*768]
  OFF_WB   = 4272384ull,     // _Float16[2048*1024]
  OFF_WQ   = 8466688ull,     // _Float16[256*512]
  OFF_WC   = 8728832ull,     // _Float16[34*768]
  OFF_K16  = 8782080ull,     // _Float16[64*2048*256]
  OFF_V16  = 75890944ull,    // _Float16[64*2048*256]
  TOTAL_FULL = 142999808ull
};

// LDS layout
#define S3_HBS  0
#define S3_QH   1536
#define S3_PL   2048
#define S3_RED  4096
#define S3_YRED 12288
#define S3_SCAL 13568
#define EX_OFF  132096
#define YS_OFF  134144
#define SMEM_BYTES 135168

struct P {
  const float *key, *val, *mask, *bq, *bc;
  const void* y;
  const _Float16 *k16, *v16;
  float *Pemb, *bb;
  _Float16 *Wa, *Wb, *Wq, *Wc;
  float *ca, *cb, *parts;
  _Float16 *ha, *hb, *ctx;
  unsigned *gctr, *grel, *qctr;
  const int* flag;
  float* out;
};

__device__ __forceinline__ void gsync(unsigned* ctr, unsigned* rel, int e) {
  __syncthreads();
  if (threadIdx.x == 0) {
    __threadfence();
    unsigned a = __hip_atomic_fetch_add(ctr, 1u, __ATOMIC_RELAXED, AGENT);
    if (a == (unsigned)(e*256 - 1)) {
      __hip_atomic_store(rel, (unsigned)e, __ATOMIC_RELEASE, AGENT);
    } else {
      while (__hip_atomic_load(rel, __ATOMIC_RELAXED, AGENT) < (unsigned)e)
        __builtin_amdgcn_s_sleep(2);
    }
    __threadfence();
  }
  __syncthreads();
}

// LSTM phase: gates = xcat @ Wcat^T (+init), elementwise cell update.
// wg owns rows n = g*512 + wg*2 + jj  (g=0..3 gates, jj=0..1), all 64 batches.
template<int K, bool YS>
__device__ __forceinline__ void lstm_phase(char* sm, int wg, int tid,
    const _Float16* src0, int len0, const _Float16* src1,
    const _Float16* Wcat, const float* accInit,
    const void* yv, int yIs64, int t,
    float* cSt, _Float16* hOut)
{
  constexpr int SK = K/8;
  const int S0 = len0/8;
  h8* xs = (h8*)sm;
  int* ysL = (int*)(sm + YS_OFF);
  if (YS && tid < 64) {
    long idx = (long)tid*250 + t;
    ysL[tid] = yIs64 ? (int)((const long long*)yv)[idx] : ((const int*)yv)[idx];
  }
  for (int i = tid; i < 64*SK; i += 512) {
    int b_ = i / SK, k8 = i % SK;
    const _Float16* s = (k8 < S0) ? (src0 + b_*len0 + k8*8)
                                  : (src1 + b_*512 + (k8 - S0)*8);
    xs[b_*(SK+1) + k8] = *(const h8*)s;
  }
  __syncthreads();
  const int b = tid & 63, r8 = tid >> 6;
  const int jj = r8 & 1, g = r8 >> 1;
  const int n = g*512 + wg*2 + jj;
  float acc = YS ? accInit[ysL[b]*2048 + n] : accInit[n];
  const h8* wrow = (const h8*)(Wcat + (size_t)n*K);
  const h8* xrow = xs + b*(SK+1);
  #pragma unroll 4
  for (int k8 = 0; k8 < SK; ++k8) acc = dot8(xrow[k8], wrow[k8], acc);
  float* ex = (float*)(sm + EX_OFF);
  ex[r8*64 + b] = acc;
  __syncthreads();
  if (tid < 128) {
    int j2 = tid >> 6, b2 = tid & 63;
    float iv = ex[(0+j2)*64+b2], fv = ex[(2+j2)*64+b2];
    float gv = ex[(4+j2)*64+b2], ov = ex[(6+j2)*64+b2];
    int ci = b2*512 + wg*2 + j2;
    float cn = sigm(fv)*cSt[ci] + sigm(iv)*tanhf(gv);
    cSt[ci] = cn;
    hOut[ci] = (_Float16)(sigm(ov)*tanhf(cn));
  }
}

// Attention phase: wg = (b = wg>>2, quarter = wg&3), 512 rows per quarter.
template<bool KV16>
__device__ __forceinline__ void attn(char* sm, const P& p, int wg, int tid, int t, int wrB) {
  const int b = wg >> 2, quarter = wg & 3;
  _Float16* hbs = (_Float16*)(sm + S3_HBS);   // [768]: h_b then ctx
  _Float16* qh  = (_Float16*)(sm + S3_QH);    // [256]
  float* pl   = (float*)(sm + S3_PL);         // [512]
  float* red  = (float*)(sm + S3_RED);        // [8][256]
  float* yred = (float*)(sm + S3_YRED);       // [34*8]
  float* scal = (float*)(sm + S3_SCAL);
  hbs[tid] = p.hb[wrB*32768 + b*512 + (tid & 511)];
  __syncthreads();
  // query (redundant per quarter)
  if (tid < 256) {
    float a = p.bq[tid];
    const h8* wr = (const h8*)(p.Wq + (size_t)tid*512);
    const h8* hx = (const h8*)hbs;
    #pragma unroll 4
    for (int k = 0; k < 64; ++k) a = dot8(hx[k], wr[k], a);
    qh[tid] = (_Float16)a;
  }
  __syncthreads();
  // energy: 16 lanes per row, 4 rows per wave per iter
  {
    const int l = tid & 63, wv = tid >> 6, lr = l >> 4, lc = l & 15;
    h2 q2[8]; float qf[16];
    if constexpr (KV16) {
      const h2* qp = (const h2*)qh;
      #pragma unroll
      for (int j = 0; j < 8; ++j) q2[j] = qp[lc*8 + j];
    } else {
      #pragma unroll
      for (int j = 0; j < 16; ++j) qf[j] = (float)qh[lc*16 + j];
    }
    const size_t base = ((size_t)b*2048 + quarter*512 + wv*64 + lr)*256 + lc*16;
    for (int it = 0; it < 16; ++it) {
      int rl = wv*64 + it*4 + lr;
      float e = 0.f;
      if constexpr (KV16) {
        const h8* kp = (const h8*)(p.k16 + base + (size_t)it*4*256);
        H8 a0, a1; a0.v = kp[0]; a1.v = kp[1];
        e = dot2(a0.p[0], q2[0], e); e = dot2(a0.p[1], q2[1], e);
        e = dot2(a0.p[2], q2[2], e); e = dot2(a0.p[3], q2[3], e);
        e = dot2(a1.p[0], q2[4], e); e = dot2(a1.p[1], q2[5], e);
        e = dot2(a1.p[2], q2[6], e); e = dot2(a1.p[3], q2[7], e);
      } else {
        const float4* kp = (const float4*)(p.key + base + (size_t)it*4*256);
        #pragma unroll
        for (int j = 0; j < 4; ++j) {
          float4 kv = kp[j];
          e += kv.x*qf[j*4+0] + kv.y*qf[j*4+1] + kv.z*qf[j*4+2] + kv.w*qf[j*4+3];
        }
      }
      e += __shfl_xor(e, 1); e += __shfl_xor(e, 2);
      e += __shfl_xor(e, 4); e += __shfl_xor(e, 8);
      if (lc == 0) {
        int r = quarter*512 + rl;
        pl[rl] = (p.mask[b*2048 + r] > 0.f) ? e : -1e9f;
      }
    }
  }
  __syncthreads();
  // partial softmax over this quarter's 512 rows
  {
    float v = pl[tid], m = v;
    #pragma unroll
    for (int s2 = 32; s2; s2 >>= 1) m = fmaxf(m, __shfl_xor(m, s2));
    if (!(tid & 63)) red[tid >> 6] = m;
    __syncthreads();
    if (!tid) {
      float mm = red[0];
      for (int i = 1; i < 8; ++i) mm = fmaxf(mm, red[i]);
      scal[0] = mm;
    }
    __syncthreads();
    float pe = __expf(v - scal[0]);
    pl[tid] = pe;
    float s = pe;
    #pragma unroll
    for (int s2 = 32; s2; s2 >>= 1) s += __shfl_xor(s, s2);
    if (!(tid & 63)) red[tid >> 6] = s;
    __syncthreads();
    if (!tid) {
      float ss = 0;
      for (int i = 0; i < 8; ++i) ss += red[i];
      scal[1] = ss;
    }
    __syncthreads();
  }
  // partial context: lanes own 4 cols, 8 row-subsets
  {
    const int c4 = (tid & 63)*4, rs = tid >> 6;
    float a0 = 0, a1 = 0, a2 = 0, a3 = 0;
    const size_t base = ((size_t)b*2048 + quarter*512 + rs*64)*256 + c4;
    for (int i = 0; i < 64; ++i) {
      float pr = pl[rs*64 + i];
      if constexpr (KV16) {
        h4 v4 = *(const h4*)(p.v16 + base + (size_t)i*256);
        a0 += pr*(float)v4[0]; a1 += pr*(float)v4[1];
        a2 += pr*(float)v4[2]; a3 += pr*(float)v4[3];
      } else {
        float4 v4 = *(const float4*)(p.val + base + (size_t)i*256);
        a0 += pr*v4.x; a1 += pr*v4.y; a2 += pr*v4.z; a3 += pr*v4.w;
      }
    }
    ((float4*)red)[tid] = make_float4(a0, a1, a2, a3);
  }
  __syncthreads();
  if (tid < 256) {
    float s = 0;
    #pragma unroll
    for (int r8 = 0; r8 < 8; ++r8) s += red[r8*256 + tid];
    float* pb = p.parts + (size_t)b*1088 + quarter*272;
    pb[tid] = s;
    if (!tid) { pb[256] = scal[0]; pb[257] = scal[1]; }
  }
  __syncthreads();
  if (!tid) {
    __threadfence();
    __hip_atomic_fetch_add(p.qctr + b, 1u, __ATOMIC_RELAXED, AGENT);
  }
  if (quarter == 0) {
    if (!tid) {
      while (__hip_atomic_load(p.qctr + b, __ATOMIC_RELAXED, AGENT) < 4u*(unsigned)(t+1))
        __builtin_amdgcn_s_sleep(2);
      __threadfence();
    }
    __syncthreads();
    if (tid < 256) {
      const float* pb = p.parts + (size_t)b*1088;
      float m0 = pb[256], s0 = pb[257], m1 = pb[272+256], s1 = pb[272+257];
      float m2 = pb[544+256], s2 = pb[544+257], m3 = pb[816+256], s3 = pb[816+257];
      float M = fmaxf(fmaxf(m0, m1), fmaxf(m2, m3));
      float w0 = __expf(m0-M), w1 = __expf(m1-M), w2 = __expf(m2-M), w3 = __expf(m3-M);
      float S = w0*s0 + w1*s1 + w2*s2 + w3*s3;
      float cv = (w0*pb[tid] + w1*pb[272+tid] + w2*pb[544+tid] + w3*pb[816+tid]) / S;
      hbs[512 + tid] = (_Float16)cv;
      p.ctx[b*256 + tid] = (_Float16)cv;
    }
    __syncthreads();
    {
      int vq = tid >> 3, ks = tid & 7;
      if (vq < 34) {
        float a = 0;
        const h8* wr = (const h8*)(p.Wc + (size_t)vq*768 + ks*96);
        const h8* xx = (const h8*)hbs + ks*12;
        #pragma unroll
        for (int i = 0; i < 12; ++i) a = dot8(xx[i], wr[i], a);
        yred[vq*8 + ks] = a;
      }
    }
    __syncthreads();
    if (tid < 34) {
      float a = p.bc[tid];
      #pragma unroll
      for (int k = 0; k < 8; ++k) a += yred[tid*8 + k];
      p.out[((size_t)b*250 + t)*34 + tid] = a;
    }
  }
}

template<bool KV16>
__global__ __launch_bounds__(512, 2) void speller_main(P p) {
  __shared__ __align__(16) char sm[SMEM_BYTES];
  const int wg = blockIdx.x, tid = threadIdx.x;
  const int y64 = *p.flag;
  int ep = 0;
  for (int t = 0; t < 250; ++t) {
    const int rd = t & 1, wr = 1 - rd;
    lstm_phase<768, true>(sm, wg, tid, p.ctx, 256, p.ha + rd*32768, p.Wa,
                          p.Pemb, p.y, y64, t, p.ca, p.ha + wr*32768);
    gsync(p.gctr, p.grel, ++ep);
    lstm_phase<1024, false>(sm, wg, tid, p.ha + wr*32768, 512, p.hb + rd*32768, p.Wb,
                            p.bb, nullptr, 0, 0, p.cb, p.hb + wr*32768);
    gsync(p.gctr, p.grel, ++ep);
    attn<KV16>(sm, p, wg, tid, t, wr);
    gsync(p.gctr, p.grel, ++ep);
  }
}

__global__ void prep_a(P p, const float* emb, const float* Wih_a, const float* Whh_a,
    const float* bih_a, const float* bhh_a, const float* Wih_b, const float* Whh_b,
    const float* bih_b, const float* bhh_b, const float* Wqf, const float* Wcf,
    unsigned* zb, int* flag)
{
  int id = blockIdx.x*blockDim.x + threadIdx.x;
  int N = gridDim.x*blockDim.x;
  for (int i = id; i < (int)ZERO_W32; i += N) zb[i] = 0u;
  for (int i = id; i < 34*2048; i += N) {
    int v = i >> 11, n = i & 2047;
    float a = bih_a[n] + bhh_a[n];
    const float4* e4 = (const float4*)(emb + v*256);
    const float4* w4 = (const float4*)(Wih_a + (size_t)n*512);
    for (int k = 0; k < 64; ++k) {
      float4 x = e4[k], w = w4[k];
      a += x.x*w.x + x.y*w.y + x.z*w.z + x.w*w.w;
    }
    p.Pemb[i] = a;
  }
  for (int i = id; i < 2048*768; i += N) {
    int n = i / 768, k = i % 768;
    float w = (k < 256) ? Wih_a[(size_t)n*512 + 256 + k] : Whh_a[(size_t)n*512 + k - 256];
    p.Wa[i] = (_Float16)w;
  }
  for (int i = id; i < 2048*1024; i += N) {
    int n = i >> 10, k = i & 1023;
    float w = (k < 512) ? Wih_b[(size_t)n*512 + k] : Whh_b[(size_t)n*512 + k - 512];
    p.Wb[i] = (_Float16)w;
  }
  for (int i = id; i < 256*512; i += N) p.Wq[i] = (_Float16)Wqf[i];
  for (int i = id; i < 34*768; i += N) p.Wc[i] = (_Float16)Wcf[i];
  for (int i = id; i < 2048; i += N) p.bb[i] = bih_b[i] + bhh_b[i];
  if (id == 0) {
    const long long* yl = (const long long*)p.y;
    int ok = 1;
    for (int i = 0; i < 200; ++i) { long long v = yl[i]; if (v < 0 || v >= 34) { ok = 0; break; } }
    *flag = ok;
  }
}

__global__ void prep_kv(const float* key, const float* val, _Float16* k16, _Float16* v16) {
  int id = blockIdx.x*blockDim.x + threadIdx.x;
  int N = gridDim.x*blockDim.x;
  const int PER = 8388608; // float4 chunks per array
  for (int i = id; i < 2*PER; i += N) {
    const float4* src; _Float16* dst; int j;
    if (i < PER) { src = (const float4*)key; dst = k16; j = i; }
    else         { src = (const float4*)val; dst = v16; j = i - PER; }
    float4 x = src[j];
    h4 o; o[0] = (_Float16)x.x; o[1] = (_Float16)x.y; o[2] = (_Float16)x.z; o[3] = (_Float16)x.w;
    *(h4*)(dst + (size_t)j*4) = o;
  }
}

extern "C" void kernel_launch(void* const* d_in, const int* in_sizes, int n_in,
                              void* d_out, int out_size, void* d_ws, size_t ws_size,
                              hipStream_t stream) {
  char* ws = (char*)d_ws;
  P p;
  p.key = (const float*)d_in[0];
  p.val = (const float*)d_in[1];
  p.y   = d_in[2];
  p.mask = (const float*)d_in[3];
  p.bq = (const float*)d_in[14];
  p.bc = (const float*)d_in[16];
  p.gctr = (unsigned*)(ws + 0);
  p.grel = (unsigned*)(ws + 4);
  p.qctr = (unsigned*)(ws + 256);
  p.ca = (float*)(ws + OFF_CA);
  p.cb = (float*)(ws + OFF_CB);
  p.ha = (_Float16*)(ws + OFF_HA);
  p.hb = (_Float16*)(ws + OFF_HB);
  p.ctx = (_Float16*)(ws + OFF_CTX);
  p.parts = (float*)(ws + OFF_PART);
  p.Pemb = (float*)(ws + OFF_PEMB);
  p.bb = (float*)(ws + OFF_BB);
  p.flag = (const int*)(ws + OFF_FLAG);
  p.Wa = (_Float16*)(ws + OFF_WA);
  p.Wb = (_Float16*)(ws + OFF_WB);
  p.Wq = (_Float16*)(ws + OFF_WQ);
  p.Wc = (_Float16*)(ws + OFF_WC);
  p.k16 = (const _Float16*)(ws + OFF_K16);
  p.v16 = (const _Float16*)(ws + OFF_V16);
  p.out = (float*)d_out;

  bool kv16 = ws_size >= (size_t)TOTAL_FULL;

  prep_a<<<dim3(1024), dim3(256), 0, stream>>>(p,
      (const float*)d_in[4], (const float*)d_in[5], (const float*)d_in[6],
      (const float*)d_in[7], (const float*)d_in[8], (const float*)d_in[9],
      (const float*)d_in[10], (const float*)d_in[11], (const float*)d_in[12],
      (const float*)d_in[13], (const float*)d_in[15],
      (unsigned*)ws, (int*)(ws + OFF_FLAG));
  if (kv16) {
    prep_kv<<<dim3(4096), dim3(256), 0, stream>>>(p.key, p.val,
        (_Float16*)(ws + OFF_K16), (_Float16*)(ws + OFF_V16));
    speller_main<true><<<dim3(256), dim3(512), 0, stream>>>(p);
  } else {
    speller_main<false><<<dim3(256), dim3(512), 0, stream>>>(p);
  }
}

// Round 2
// 39777.997 us; speedup vs baseline: 1.0451x; 1.0451x over previous
//
#include <hip/hip_runtime.h>

typedef _Float16 h2 __attribute__((ext_vector_type(2)));
typedef _Float16 h4 __attribute__((ext_vector_type(4)));
typedef _Float16 h8 __attribute__((ext_vector_type(8)));
union H8 { h8 v; h2 p[4]; };

#define AGENT __HIP_MEMORY_SCOPE_AGENT
#define NT 1024

__device__ __forceinline__ float dot2(h2 a, h2 b, float c) {
#if __has_builtin(__builtin_amdgcn_fdot2)
  return __builtin_amdgcn_fdot2(a, b, c, false);
#else
  return c + (float)a[0]*(float)b[0] + (float)a[1]*(float)b[1];
#endif
}
__device__ __forceinline__ float dot8(h8 x, h8 w, float acc) {
  H8 a, b; a.v = x; b.v = w;
  acc = dot2(a.p[0], b.p[0], acc); acc = dot2(a.p[1], b.p[1], acc);
  acc = dot2(a.p[2], b.p[2], acc); acc = dot2(a.p[3], b.p[3], acc);
  return acc;
}
__device__ __forceinline__ float sigm(float x){ return 1.f/(1.f+__expf(-x)); }

// ---------------- workspace layout (bytes) — IDENTICAL to round 1 ----------
enum : unsigned long long {
  OFF_CA   = 4096ull,        // float[64*512]
  OFF_CB   = 135168ull,      // float[64*512]
  OFF_HA   = 266240ull,      // _Float16[2][64*512]
  OFF_HB   = 397312ull,      // _Float16[2][64*512]
  OFF_CTX  = 528384ull,      // _Float16[64*256]
  ZERO_W32 = 140288ull,      // words zeroed: 0 .. 561152
  OFF_PART = 561152ull,      // float[64][4][272]
  OFF_PEMB = 839680ull,      // float[34*2048]
  OFF_BB   = 1118208ull,     // float[2048]
  OFF_FLAG = 1126400ull,     // int
  OFF_WA   = 1126656ull,     // _Float16[2048*768]
  OFF_WB   = 4272384ull,     // _Float16[2048*1024]
  OFF_WQ   = 8466688ull,     // _Float16[256*512]
  OFF_WC   = 8728832ull,     // _Float16[34*768]
  OFF_K16  = 8782080ull,     // _Float16[64*2048*256]
  OFF_V16  = 75890944ull,    // _Float16[64*2048*256]
  TOTAL_FULL = 142999808ull
};

// LDS layout
#define S3_HBS  0
#define S3_QH   1536
#define S3_PL   2048
#define S3_RED  4096       // float[32][256] = 32KB -> 36864
#define S3_YRED 36864      // float[34*8]
#define S3_SCAL 38016
#define EX_OFF  132096     // float[16][64] = 4KB
#define YS_OFF  136192     // int[64]
#define SMEM_BYTES 136448

struct P {
  const float *key, *val, *mask, *bq, *bc;
  const void* y;
  const _Float16 *k16, *v16;
  float *Pemb, *bb;
  _Float16 *Wa, *Wb, *Wq, *Wc;
  float *ca, *cb, *parts;
  _Float16 *ha, *hb, *ctx;
  unsigned *gctr, *grel, *qctr;
  const int* flag;
  float* out;
};

__device__ __forceinline__ void gsync(unsigned* ctr, unsigned* rel, int e) {
  __syncthreads();
  if (threadIdx.x == 0) {
    __threadfence();
    unsigned a = __hip_atomic_fetch_add(ctr, 1u, __ATOMIC_RELAXED, AGENT);
    if (a == (unsigned)(e*256 - 1)) {
      __hip_atomic_store(rel, (unsigned)e, __ATOMIC_RELEASE, AGENT);
    } else {
      while (__hip_atomic_load(rel, __ATOMIC_RELAXED, AGENT) < (unsigned)e)
        __builtin_amdgcn_s_sleep(2);
    }
    __threadfence();
  }
  __syncthreads();
}

// LSTM phase: gates = xcat @ Wcat^T (+init). wg owns unit u=wg*2+jj (jj=0,1)
// for all 4 gates, all 64 batches. 16 row-slots: rs = s*8 + g*2 + jj
// (s in {0,1} splits K interleaved by h8 unit).
template<int K, bool YS>
__device__ __forceinline__ void lstm_phase(char* sm, int wg, int tid,
    const _Float16* src0, int len0, const _Float16* src1,
    const _Float16* Wcat, const float* accInit,
    const void* yv, int yIs64, int t,
    float* cSt, _Float16* hOut)
{
  constexpr int SK = K/8;
  const int S0 = len0/8;
  h8* xs = (h8*)sm;                       // [64][SK+1]
  int* ysL = (int*)(sm + YS_OFF);
  if (YS && tid < 64) {
    long idx = (long)tid*250 + t;
    ysL[tid] = yIs64 ? (int)((const long long*)yv)[idx] : ((const int*)yv)[idx];
  }
  for (int i = tid; i < 64*SK; i += NT) {
    int b_ = i / SK, k8 = i % SK;
    const _Float16* s = (k8 < S0) ? (src0 + b_*len0 + k8*8)
                                  : (src1 + b_*512 + (k8 - S0)*8);
    xs[b_*(SK+1) + k8] = *(const h8*)s;
  }
  __syncthreads();
  const int b = tid & 63, rs = tid >> 6;          // rs in [0,16)
  const int jj = rs & 1, g = (rs >> 1) & 3, s = rs >> 3;
  const int n = g*512 + wg*2 + jj;
  float acc = 0.f;
  const h8* wrow = (const h8*)(Wcat + (size_t)n*K);
  const h8* xrow = xs + b*(SK+1);
  #pragma unroll 8
  for (int m = 0; m < SK/2; ++m) acc = dot8(xrow[2*m+s], wrow[2*m+s], acc);
  float* ex = (float*)(sm + EX_OFF);
  ex[rs*64 + b] = acc;
  __syncthreads();
  if (tid < 128) {
    int j2 = tid >> 6, b2 = tid & 63;
    int n0 = wg*2 + j2;
    float i0, i1, i2, i3;
    if (YS) {
      const float* pe = accInit + (size_t)ysL[b2]*2048 + n0;
      i0 = pe[0]; i1 = pe[512]; i2 = pe[1024]; i3 = pe[1536];
    } else {
      i0 = accInit[n0]; i1 = accInit[512+n0]; i2 = accInit[1024+n0]; i3 = accInit[1536+n0];
    }
    float iv = ex[(0+j2)*64+b2] + ex[(8+0+j2)*64+b2] + i0;
    float fv = ex[(2+j2)*64+b2] + ex[(8+2+j2)*64+b2] + i1;
    float gv = ex[(4+j2)*64+b2] + ex[(8+4+j2)*64+b2] + i2;
    float ov = ex[(6+j2)*64+b2] + ex[(8+6+j2)*64+b2] + i3;
    int ci = b2*512 + wg*2 + j2;
    float cn = sigm(fv)*cSt[ci] + sigm(iv)*tanhf(gv);
    cSt[ci] = cn;
    hOut[ci] = (_Float16)(sigm(ov)*tanhf(cn));
  }
}

// Attention: wg = (b = wg>>2, quarter = wg&3), 512 rows per quarter.
template<bool KV16>
__device__ __forceinline__ void attn(char* sm, const P& p, int wg, int tid, int t, int wrB) {
  const int b = wg >> 2, quarter = wg & 3;
  _Float16* hbs = (_Float16*)(sm + S3_HBS);   // [768]: h_b then ctx
  _Float16* qh  = (_Float16*)(sm + S3_QH);    // [256]
  float* pl   = (float*)(sm + S3_PL);         // [512]
  float* red  = (float*)(sm + S3_RED);        // [32][256]
  float* yred = (float*)(sm + S3_YRED);       // [34*8]
  float* scal = (float*)(sm + S3_SCAL);
  if (tid < 512) hbs[tid] = p.hb[wrB*32768 + b*512 + tid];
  __syncthreads();
  // query (redundant per quarter)
  if (tid < 256) {
    float a = p.bq[tid];
    const h8* wr = (const h8*)(p.Wq + (size_t)tid*512);
    const h8* hx = (const h8*)hbs;
    #pragma unroll 8
    for (int k = 0; k < 64; ++k) a = dot8(hx[k], wr[k], a);
    qh[tid] = (_Float16)a;
  }
  __syncthreads();
  // energy: 16 lanes per row, 4 rows per wave per iter, 8 iters, 16 waves
  {
    const int l = tid & 63, wv = tid >> 6, lr = l >> 4, lc = l & 15;
    const int rbase = quarter*512 + wv*32 + lr;
    if constexpr (KV16) {
      h2 q2[8];
      const h2* qp = (const h2*)qh;
      #pragma unroll
      for (int j = 0; j < 8; ++j) q2[j] = qp[lc*8 + j];
      const _Float16* kbase = p.k16 + ((size_t)b*2048 + rbase)*256 + lc*16;
      h8 ka[8], kb[8];
      #pragma unroll
      for (int it = 0; it < 8; ++it) {
        const h8* kp = (const h8*)(kbase + (size_t)it*4*256);
        ka[it] = kp[0]; kb[it] = kp[1];
      }
      #pragma unroll
      for (int it = 0; it < 8; ++it) {
        float e = 0.f;
        H8 a0, a1; a0.v = ka[it]; a1.v = kb[it];
        e = dot2(a0.p[0], q2[0], e); e = dot2(a0.p[1], q2[1], e);
        e = dot2(a0.p[2], q2[2], e); e = dot2(a0.p[3], q2[3], e);
        e = dot2(a1.p[0], q2[4], e); e = dot2(a1.p[1], q2[5], e);
        e = dot2(a1.p[2], q2[6], e); e = dot2(a1.p[3], q2[7], e);
        e += __shfl_xor(e, 1); e += __shfl_xor(e, 2);
        e += __shfl_xor(e, 4); e += __shfl_xor(e, 8);
        if (lc == 0) {
          int rl = wv*32 + it*4 + lr;
          pl[rl] = (p.mask[b*2048 + quarter*512 + rl] > 0.f) ? e : -1e9f;
        }
      }
    } else {
      float qf[16];
      #pragma unroll
      for (int j = 0; j < 16; ++j) qf[j] = (float)qh[lc*16 + j];
      const float* kbase = p.key + ((size_t)b*2048 + rbase)*256 + lc*16;
      for (int ii = 0; ii < 4; ++ii) {
        float4 kv[2][4];
        #pragma unroll
        for (int jt = 0; jt < 2; ++jt) {
          const float4* kp = (const float4*)(kbase + (size_t)(ii*2+jt)*4*256);
          #pragma unroll
          for (int j = 0; j < 4; ++j) kv[jt][j] = kp[j];
        }
        #pragma unroll
        for (int jt = 0; jt < 2; ++jt) {
          float e = 0.f;
          #pragma unroll
          for (int j = 0; j < 4; ++j)
            e += kv[jt][j].x*qf[j*4+0] + kv[jt][j].y*qf[j*4+1]
               + kv[jt][j].z*qf[j*4+2] + kv[jt][j].w*qf[j*4+3];
          e += __shfl_xor(e, 1); e += __shfl_xor(e, 2);
          e += __shfl_xor(e, 4); e += __shfl_xor(e, 8);
          if (lc == 0) {
            int rl = wv*32 + (ii*2+jt)*4 + lr;
            pl[rl] = (p.mask[b*2048 + quarter*512 + rl] > 0.f) ? e : -1e9f;
          }
        }
      }
    }
  }
  __syncthreads();
  // partial softmax over this quarter's 512 rows (threads 0..511)
  {
    float v = (tid < 512) ? pl[tid] : -1e30f;
    float m = v;
    #pragma unroll
    for (int s2 = 32; s2; s2 >>= 1) m = fmaxf(m, __shfl_xor(m, s2));
    if (tid < 512 && !(tid & 63)) red[tid >> 6] = m;
    __syncthreads();
    if (!tid) {
      float mm = red[0];
      for (int i = 1; i < 8; ++i) mm = fmaxf(mm, red[i]);
      scal[0] = mm;
    }
    __syncthreads();
    float pe = 0.f;
    if (tid < 512) { pe = __expf(v - scal[0]); pl[tid] = pe; }
    float s = pe;
    #pragma unroll
    for (int s2 = 32; s2; s2 >>= 1) s += __shfl_xor(s, s2);
    if (tid < 512 && !(tid & 63)) red[tid >> 6] = s;
    __syncthreads();
    if (!tid) {
      float ss = 0;
      for (int i = 0; i < 8; ++i) ss += red[i];
      scal[1] = ss;
    }
    __syncthreads();
  }
  // partial context: 32 lanes x 8 cols (16B), 32 row-subsets x 16 rows
  {
    const int l32 = tid & 31, rs32 = tid >> 5;
    float a[8] = {0,0,0,0,0,0,0,0};
    if constexpr (KV16) {
      const _Float16* vbase = p.v16 + ((size_t)b*2048 + quarter*512 + rs32*16)*256 + l32*8;
      #pragma unroll
      for (int ii = 0; ii < 2; ++ii) {
        h8 vv[8];
        #pragma unroll
        for (int j = 0; j < 8; ++j) vv[j] = *(const h8*)(vbase + (size_t)(ii*8+j)*256);
        #pragma unroll
        for (int j = 0; j < 8; ++j) {
          float pr = pl[rs32*16 + ii*8 + j];
          #pragma unroll
          for (int c = 0; c < 8; ++c) a[c] += pr * (float)vv[j][c];
        }
      }
    } else {
      const float* vbase = p.val + ((size_t)b*2048 + quarter*512 + rs32*16)*256 + l32*8;
      for (int ii = 0; ii < 4; ++ii) {
        float4 v4[4][2];
        #pragma unroll
        for (int j = 0; j < 4; ++j) {
          const float4* vp = (const float4*)(vbase + (size_t)(ii*4+j)*256);
          v4[j][0] = vp[0]; v4[j][1] = vp[1];
        }
        #pragma unroll
        for (int j = 0; j < 4; ++j) {
          float pr = pl[rs32*16 + ii*4 + j];
          a[0] += pr*v4[j][0].x; a[1] += pr*v4[j][0].y;
          a[2] += pr*v4[j][0].z; a[3] += pr*v4[j][0].w;
          a[4] += pr*v4[j][1].x; a[5] += pr*v4[j][1].y;
          a[6] += pr*v4[j][1].z; a[7] += pr*v4[j][1].w;
        }
      }
    }
    float* rd = red + rs32*256 + l32*8;
    ((float4*)rd)[0] = make_float4(a[0], a[1], a[2], a[3]);
    ((float4*)rd)[1] = make_float4(a[4], a[5], a[6], a[7]);
  }
  __syncthreads();
  if (tid < 256) {
    float s = 0;
    #pragma unroll
    for (int r = 0; r < 32; ++r) s += red[r*256 + tid];
    float* pb = p.parts + (size_t)b*1088 + quarter*272;
    pb[tid] = s;
    if (!tid) { pb[256] = scal[0]; pb[257] = scal[1]; }
  }
  __syncthreads();
  if (!tid) {
    __threadfence();
    __hip_atomic_fetch_add(p.qctr + b, 1u, __ATOMIC_RELAXED, AGENT);
  }
  if (quarter == 0) {
    if (!tid) {
      while (__hip_atomic_load(p.qctr + b, __ATOMIC_RELAXED, AGENT) < 4u*(unsigned)(t+1))
        __builtin_amdgcn_s_sleep(2);
      __threadfence();
    }
    __syncthreads();
    if (tid < 256) {
      const float* pb = p.parts + (size_t)b*1088;
      float m0 = pb[256], s0 = pb[257], m1 = pb[272+256], s1 = pb[272+257];
      float m2 = pb[544+256], s2 = pb[544+257], m3 = pb[816+256], s3 = pb[816+257];
      float M = fmaxf(fmaxf(m0, m1), fmaxf(m2, m3));
      float w0 = __expf(m0-M), w1 = __expf(m1-M), w2 = __expf(m2-M), w3 = __expf(m3-M);
      float S = w0*s0 + w1*s1 + w2*s2 + w3*s3;
      float cv = (w0*pb[tid] + w1*pb[272+tid] + w2*pb[544+tid] + w3*pb[816+tid]) / S;
      hbs[512 + tid] = (_Float16)cv;
      p.ctx[b*256 + tid] = (_Float16)cv;
    }
    __syncthreads();
    {
      int vq = tid >> 3, ks = tid & 7;
      if (vq < 34) {
        float a = 0;
        const h8* wr = (const h8*)(p.Wc + (size_t)vq*768 + ks*96);
        const h8* xx = (const h8*)hbs + ks*12;
        #pragma unroll
        for (int i = 0; i < 12; ++i) a = dot8(xx[i], wr[i], a);
        yred[vq*8 + ks] = a;
      }
    }
    __syncthreads();
    if (tid < 34) {
      float a = p.bc[tid];
      #pragma unroll
      for (int k = 0; k < 8; ++k) a += yred[tid*8 + k];
      p.out[((size_t)b*250 + t)*34 + tid] = a;
    }
  }
}

template<bool KV16>
__global__ __launch_bounds__(NT, 4) void speller_main(P p) {
  __shared__ __align__(16) char sm[SMEM_BYTES];
  const int wg = blockIdx.x, tid = threadIdx.x;
  const int y64 = *p.flag;
  int ep = 0;
  for (int t = 0; t < 250; ++t) {
    const int rd = t & 1, wr = 1 - rd;
    lstm_phase<768, true>(sm, wg, tid, p.ctx, 256, p.ha + rd*32768, p.Wa,
                          p.Pemb, p.y, y64, t, p.ca, p.ha + wr*32768);
    gsync(p.gctr, p.grel, ++ep);
    lstm_phase<1024, false>(sm, wg, tid, p.ha + wr*32768, 512, p.hb + rd*32768, p.Wb,
                            p.bb, nullptr, 0, 0, p.cb, p.hb + wr*32768);
    gsync(p.gctr, p.grel, ++ep);
    attn<KV16>(sm, p, wg, tid, t, wr);
    gsync(p.gctr, p.grel, ++ep);
  }
}

__global__ void prep_a(P p, const float* emb, const float* Wih_a, const float* Whh_a,
    const float* bih_a, const float* bhh_a, const float* Wih_b, const float* Whh_b,
    const float* bih_b, const float* bhh_b, const float* Wqf, const float* Wcf,
    unsigned* zb, int* flag)
{
  int id = blockIdx.x*blockDim.x + threadIdx.x;
  int N = gridDim.x*blockDim.x;
  for (int i = id; i < (int)ZERO_W32; i += N) zb[i] = 0u;
  for (int i = id; i < 34*2048; i += N) {
    int v = i >> 11, n = i & 2047;
    float a = bih_a[n] + bhh_a[n];
    const float4* e4 = (const float4*)(emb + v*256);
    const float4* w4 = (const float4*)(Wih_a + (size_t)n*512);
    for (int k = 0; k < 64; ++k) {
      float4 x = e4[k], w = w4[k];
      a += x.x*w.x + x.y*w.y + x.z*w.z + x.w*w.w;
    }
    p.Pemb[i] = a;
  }
  for (int i = id; i < 2048*768; i += N) {
    int n = i / 768, k = i % 768;
    float w = (k < 256) ? Wih_a[(size_t)n*512 + 256 + k] : Whh_a[(size_t)n*512 + k - 256];
    p.Wa[i] = (_Float16)w;
  }
  for (int i = id; i < 2048*1024; i += N) {
    int n = i >> 10, k = i & 1023;
    float w = (k < 512) ? Wih_b[(size_t)n*512 + k] : Whh_b[(size_t)n*512 + k - 512];
    p.Wb[i] = (_Float16)w;
  }
  for (int i = id; i < 256*512; i += N) p.Wq[i] = (_Float16)Wqf[i];
  for (int i = id; i < 34*768; i += N) p.Wc[i] = (_Float16)Wcf[i];
  for (int i = id; i < 2048; i += N) p.bb[i] = bih_b[i] + bhh_b[i];
  if (id == 0) {
    const long long* yl = (const long long*)p.y;
    int ok = 1;
    for (int i = 0; i < 200; ++i) { long long v = yl[i]; if (v < 0 || v >= 34) { ok = 0; break; } }
    *flag = ok;
  }
}

__global__ void prep_kv(const float* key, const float* val, _Float16* k16, _Float16* v16) {
  int id = blockIdx.x*blockDim.x + threadIdx.x;
  int N = gridDim.x*blockDim.x;
  const int PER = 8388608; // float4 chunks per array
  for (int i = id; i < 2*PER; i += N) {
    const float4* src; _Float16* dst; int j;
    if (i < PER) { src = (const float4*)key; dst = k16; j = i; }
    else         { src = (const float4*)val; dst = v16; j = i - PER; }
    float4 x = src[j];
    h4 o; o[0] = (_Float16)x.x; o[1] = (_Float16)x.y; o[2] = (_Float16)x.z; o[3] = (_Float16)x.w;
    *(h4*)(dst + (size_t)j*4) = o;
  }
}

extern "C" void kernel_launch(void* const* d_in, const int* in_sizes, int n_in,
                              void* d_out, int out_size, void* d_ws, size_t ws_size,
                              hipStream_t stream) {
  char* ws = (char*)d_ws;
  P p;
  p.key = (const float*)d_in[0];
  p.val = (const float*)d_in[1];
  p.y   = d_in[2];
  p.mask = (const float*)d_in[3];
  p.bq = (const float*)d_in[14];
  p.bc = (const float*)d_in[16];
  p.gctr = (unsigned*)(ws + 0);
  p.grel = (unsigned*)(ws + 4);
  p.qctr = (unsigned*)(ws + 256);
  p.ca = (float*)(ws + OFF_CA);
  p.cb = (float*)(ws + OFF_CB);
  p.ha = (_Float16*)(ws + OFF_HA);
  p.hb = (_Float16*)(ws + OFF_HB);
  p.ctx = (_Float16*)(ws + OFF_CTX);
  p.parts = (float*)(ws + OFF_PART);
  p.Pemb = (float*)(ws + OFF_PEMB);
  p.bb = (float*)(ws + OFF_BB);
  p.flag = (const int*)(ws + OFF_FLAG);
  p.Wa = (_Float16*)(ws + OFF_WA);
  p.Wb = (_Float16*)(ws + OFF_WB);
  p.Wq = (_Float16*)(ws + OFF_WQ);
  p.Wc = (_Float16*)(ws + OFF_WC);
  p.k16 = (const _Float16*)(ws + OFF_K16);
  p.v16 = (const _Float16*)(ws + OFF_V16);
  p.out = (float*)d_out;

  bool kv16 = ws_size >= (size_t)TOTAL_FULL;

  prep_a<<<dim3(1024), dim3(256), 0, stream>>>(p,
      (const float*)d_in[4], (const float*)d_in[5], (const float*)d_in[6],
      (const float*)d_in[7], (const float*)d_in[8], (const float*)d_in[9],
      (const float*)d_in[10], (const float*)d_in[11], (const float*)d_in[12],
      (const float*)d_in[13], (const float*)d_in[15],
      (unsigned*)ws, (int*)(ws + OFF_FLAG));
  if (kv16) {
    prep_kv<<<dim3(4096), dim3(256), 0, stream>>>(p.key, p.val,
        (_Float16*)(ws + OFF_K16), (_Float16*)(ws + OFF_V16));
    speller_main<true><<<dim3(256), dim3(NT), 0, stream>>>(p);
  } else {
    speller_main<false><<<dim3(256), dim3(NT), 0, stream>>>(p);
  }
}

// Round 3
// 33370.413 us; speedup vs baseline: 1.2458x; 1.1920x over previous
//
#include <hip/hip_runtime.h>

typedef _Float16 h2 __attribute__((ext_vector_type(2)));
typedef _Float16 h4 __attribute__((ext_vector_type(4)));
typedef _Float16 h8 __attribute__((ext_vector_type(8)));
union H8 { h8 v; h2 p[4]; };

#define AGENT __HIP_MEMORY_SCOPE_AGENT
#define NT 1024

__device__ __forceinline__ float dot2(h2 a, h2 b, float c) {
#if __has_builtin(__builtin_amdgcn_fdot2)
  return __builtin_amdgcn_fdot2(a, b, c, false);
#else
  return c + (float)a[0]*(float)b[0] + (float)a[1]*(float)b[1];
#endif
}
__device__ __forceinline__ float dot8(h8 x, h8 w, float acc) {
  H8 a, b; a.v = x; b.v = w;
  acc = dot2(a.p[0], b.p[0], acc); acc = dot2(a.p[1], b.p[1], acc);
  acc = dot2(a.p[2], b.p[2], acc); acc = dot2(a.p[3], b.p[3], acc);
  return acc;
}
__device__ __forceinline__ float sigm(float x){ return 1.f/(1.f+__expf(-x)); }

// ---------------- workspace layout (bytes) ----------------
// grel @128. Sync flags each own a 128B line (no same-line RMW serialization).
enum : unsigned long long {
  OFF_CA    = 4096ull,       // float[64*512]
  OFF_CB    = 135168ull,     // float[64*512]
  OFF_HA    = 266240ull,     // _Float16[2][64*512]
  OFF_HB    = 397312ull,     // _Float16[2][64*512]
  OFF_CTX   = 528384ull,     // _Float16[64*256]
  OFF_FLAGS = 561152ull,     // int[256] @128B stride (32KB)
  OFF_CFLAG = 593920ull,     // int[64]  @128B stride (8KB)
  OFF_QCTR  = 602112ull,     // uint[64] @128B stride (8KB)
  ZERO_W32  = 152576ull,     // words zeroed: bytes 0 .. 610304
  OFF_PART  = 610304ull,     // float[64][4][272]
  OFF_PEMB  = 888832ull,     // float[34*2048]
  OFF_BB    = 1167360ull,    // float[2048]
  OFF_FLAG  = 1175552ull,    // int (y-is-64bit flag)
  OFF_WA    = 1175808ull,    // _Float16[2048*768]
  OFF_WB    = 4321536ull,    // _Float16[2048*1024]
  OFF_WQ    = 8515840ull,    // _Float16[256*512]
  OFF_WC    = 8777984ull,    // _Float16[34*768]
  OFF_K16   = 8830976ull,    // _Float16[64*2048*256]
  OFF_V16   = 75939840ull,   // _Float16[64*2048*256]
  TOTAL_FULL = 143048704ull
};

// LDS layout
#define S3_HBS  0
#define S3_QH   1536
#define S3_PL   2048
#define S3_RED  4096       // float[32][256] = 32KB
#define S3_YRED 36864      // float[34*8]
#define S3_SCAL 38016
#define EX_OFF  132096     // float[16][64]
#define YS_OFF  136192     // int[64]
#define SMEM_BYTES 136448

struct P {
  const float *key, *val, *mask, *bq, *bc;
  const void* y;
  const _Float16 *k16, *v16;
  float *Pemb, *bb;
  _Float16 *Wa, *Wb, *Wq, *Wc;
  float *ca, *cb, *parts;
  _Float16 *ha, *hb, *ctx;
  int *flags, *cflag, *grel;
  unsigned *qctr;
  const int* flag;
  float* out;
};

// Flag-array grid barrier: arrival = release-store to own line (parallel);
// wg0 sweeps 256 flags, releases grel; others poll grel.
__device__ __forceinline__ void gsync(const P& p, int e) {
  const int tid = threadIdx.x, wg = blockIdx.x;
  __syncthreads();
  if (tid == 0) {
    __threadfence();
    __hip_atomic_store(p.flags + (size_t)wg*32, e, __ATOMIC_RELEASE, AGENT);
  }
  if (wg == 0) {
    for (;;) {
      int ok = 1;
      if (tid < 256) ok = (__hip_atomic_load(p.flags + (size_t)tid*32, __ATOMIC_RELAXED, AGENT) >= e);
      if (__syncthreads_and(ok)) break;
    }
    if (tid == 0) {
      __threadfence();
      __hip_atomic_store(p.grel, e, __ATOMIC_RELEASE, AGENT);
    }
  } else if (tid == 0) {
    while (__hip_atomic_load(p.grel, __ATOMIC_RELAXED, AGENT) < e)
      __builtin_amdgcn_s_sleep(2);
    __threadfence();
  }
  __syncthreads();
}

// LSTM phase: gates = xcat @ Wcat^T (+init). wg owns units wg*2+jj (jj=0,1)
// for all 4 gates, all 64 batches. 16 row-slots: contiguous K-split by s.
template<int K, bool YS>
__device__ __forceinline__ void lstm_phase(char* sm, int wg, int tid,
    const _Float16* src0, int len0, const _Float16* src1,
    const _Float16* Wcat, const float* accInit,
    const void* yv, int yIs64, int t,
    float* cSt, _Float16* hOut)
{
  constexpr int SK = K/8;
  const int S0 = len0/8;
  h8* xs = (h8*)sm;                       // [64][SK+1]
  int* ysL = (int*)(sm + YS_OFF);
  if (YS && tid < 64) {
    long idx = (long)tid*250 + t;
    ysL[tid] = yIs64 ? (int)((const long long*)yv)[idx] : ((const int*)yv)[idx];
  }
  for (int i = tid; i < 64*SK; i += NT) {
    int b_ = i / SK, k8 = i % SK;
    const _Float16* s = (k8 < S0) ? (src0 + b_*len0 + k8*8)
                                  : (src1 + b_*512 + (k8 - S0)*8);
    xs[b_*(SK+1) + k8] = *(const h8*)s;
  }
  __syncthreads();
  const int b = tid & 63, rs = tid >> 6;          // rs in [0,16)
  const int jj = rs & 1, g = (rs >> 1) & 3, s = rs >> 3;
  const int n = g*512 + wg*2 + jj;
  float acc = 0.f;
  const h8* wrow = (const h8*)(Wcat + (size_t)n*K) + s*(SK/2);
  const h8* xrow = xs + b*(SK+1) + s*(SK/2);
  #pragma unroll 8
  for (int m = 0; m < SK/2; ++m) acc = dot8(xrow[m], wrow[m], acc);
  float* ex = (float*)(sm + EX_OFF);
  ex[rs*64 + b] = acc;
  __syncthreads();
  if (tid < 128) {
    int j2 = tid >> 6, b2 = tid & 63;
    int n0 = wg*2 + j2;
    float i0, i1, i2, i3;
    if (YS) {
      const float* pe = accInit + (size_t)ysL[b2]*2048 + n0;
      i0 = pe[0]; i1 = pe[512]; i2 = pe[1024]; i3 = pe[1536];
    } else {
      i0 = accInit[n0]; i1 = accInit[512+n0]; i2 = accInit[1024+n0]; i3 = accInit[1536+n0];
    }
    float iv = ex[(0+j2)*64+b2] + ex[(8+0+j2)*64+b2] + i0;
    float fv = ex[(2+j2)*64+b2] + ex[(8+2+j2)*64+b2] + i1;
    float gv = ex[(4+j2)*64+b2] + ex[(8+4+j2)*64+b2] + i2;
    float ov = ex[(6+j2)*64+b2] + ex[(8+6+j2)*64+b2] + i3;
    int ci = b2*512 + wg*2 + j2;
    float cn = sigm(fv)*cSt[ci] + sigm(iv)*tanhf(gv);
    cSt[ci] = cn;
    hOut[ci] = (_Float16)(sigm(ov)*tanhf(cn));
  }
}

// Attention: wg = (b = wg>>2, quarter = wg&3), 512 rows per quarter.
template<bool KV16>
__device__ __forceinline__ void attn(char* sm, const P& p, int wg, int tid, int t,
                                     int wrB, unsigned mbits) {
  const int b = wg >> 2, quarter = wg & 3;
  _Float16* hbs = (_Float16*)(sm + S3_HBS);   // [768]: h_b then ctx
  _Float16* qh  = (_Float16*)(sm + S3_QH);    // [256]
  float* pl   = (float*)(sm + S3_PL);         // [512]
  float* red  = (float*)(sm + S3_RED);        // [32][256]
  float* yred = (float*)(sm + S3_YRED);       // [34*8]
  float* scal = (float*)(sm + S3_SCAL);
  if (tid < 512) hbs[tid] = p.hb[wrB*32768 + b*512 + tid];
  __syncthreads();
  // query (redundant per quarter)
  if (tid < 256) {
    float a = p.bq[tid];
    const h8* wr = (const h8*)(p.Wq + (size_t)tid*512);
    const h8* hx = (const h8*)hbs;
    #pragma unroll 8
    for (int k = 0; k < 64; ++k) a = dot8(hx[k], wr[k], a);
    qh[tid] = (_Float16)a;
  }
  __syncthreads();
  // energy: 16 lanes per row, 4 rows per wave per iter, 8 iters, 16 waves
  {
    const int l = tid & 63, wv = tid >> 6, lr = l >> 4, lc = l & 15;
    const int rbase = quarter*512 + wv*32 + lr;
    if constexpr (KV16) {
      h2 q2[8];
      const h2* qp = (const h2*)qh;
      #pragma unroll
      for (int j = 0; j < 8; ++j) q2[j] = qp[lc*8 + j];
      const _Float16* kbase = p.k16 + ((size_t)b*2048 + rbase)*256 + lc*16;
      h8 ka[8], kb[8];
      #pragma unroll
      for (int it = 0; it < 8; ++it) {
        const h8* kp = (const h8*)(kbase + (size_t)it*4*256);
        ka[it] = kp[0]; kb[it] = kp[1];
      }
      #pragma unroll
      for (int it = 0; it < 8; ++it) {
        float e = 0.f;
        H8 a0, a1; a0.v = ka[it]; a1.v = kb[it];
        e = dot2(a0.p[0], q2[0], e); e = dot2(a0.p[1], q2[1], e);
        e = dot2(a0.p[2], q2[2], e); e = dot2(a0.p[3], q2[3], e);
        e = dot2(a1.p[0], q2[4], e); e = dot2(a1.p[1], q2[5], e);
        e = dot2(a1.p[2], q2[6], e); e = dot2(a1.p[3], q2[7], e);
        e += __shfl_xor(e, 1); e += __shfl_xor(e, 2);
        e += __shfl_xor(e, 4); e += __shfl_xor(e, 8);
        if (lc == 0) {
          int rl = wv*32 + it*4 + lr;
          pl[rl] = ((mbits >> it) & 1u) ? e : -1e9f;
        }
      }
    } else {
      float qf[16];
      #pragma unroll
      for (int j = 0; j < 16; ++j) qf[j] = (float)qh[lc*16 + j];
      const float* kbase = p.key + ((size_t)b*2048 + rbase)*256 + lc*16;
      for (int ii = 0; ii < 4; ++ii) {
        float4 kv[2][4];
        #pragma unroll
        for (int jt = 0; jt < 2; ++jt) {
          const float4* kp = (const float4*)(kbase + (size_t)(ii*2+jt)*4*256);
          #pragma unroll
          for (int j = 0; j < 4; ++j) kv[jt][j] = kp[j];
        }
        #pragma unroll
        for (int jt = 0; jt < 2; ++jt) {
          float e = 0.f;
          #pragma unroll
          for (int j = 0; j < 4; ++j)
            e += kv[jt][j].x*qf[j*4+0] + kv[jt][j].y*qf[j*4+1]
               + kv[jt][j].z*qf[j*4+2] + kv[jt][j].w*qf[j*4+3];
          e += __shfl_xor(e, 1); e += __shfl_xor(e, 2);
          e += __shfl_xor(e, 4); e += __shfl_xor(e, 8);
          if (lc == 0) {
            int it = ii*2 + jt;
            int rl = wv*32 + it*4 + lr;
            pl[rl] = ((mbits >> it) & 1u) ? e : -1e9f;
          }
        }
      }
    }
  }
  __syncthreads();
  // partial softmax over this quarter's 512 rows (threads 0..511)
  {
    float v = (tid < 512) ? pl[tid] : -1e30f;
    float m = v;
    #pragma unroll
    for (int s2 = 32; s2; s2 >>= 1) m = fmaxf(m, __shfl_xor(m, s2));
    if (tid < 512 && !(tid & 63)) red[tid >> 6] = m;
    __syncthreads();
    if (!tid) {
      float mm = red[0];
      for (int i = 1; i < 8; ++i) mm = fmaxf(mm, red[i]);
      scal[0] = mm;
    }
    __syncthreads();
    float pe = 0.f;
    if (tid < 512) { pe = __expf(v - scal[0]); pl[tid] = pe; }
    float s = pe;
    #pragma unroll
    for (int s2 = 32; s2; s2 >>= 1) s += __shfl_xor(s, s2);
    if (tid < 512 && !(tid & 63)) red[tid >> 6] = s;
    __syncthreads();
    if (!tid) {
      float ss = 0;
      for (int i = 0; i < 8; ++i) ss += red[i];
      scal[1] = ss;
    }
    __syncthreads();
  }
  // partial context: 32 lanes x 8 cols (16B), 32 row-subsets x 16 rows
  {
    const int l32 = tid & 31, rs32 = tid >> 5;
    float a[8] = {0,0,0,0,0,0,0,0};
    if constexpr (KV16) {
      const _Float16* vbase = p.v16 + ((size_t)b*2048 + quarter*512 + rs32*16)*256 + l32*8;
      #pragma unroll
      for (int ii = 0; ii < 2; ++ii) {
        h8 vv[8];
        #pragma unroll
        for (int j = 0; j < 8; ++j) vv[j] = *(const h8*)(vbase + (size_t)(ii*8+j)*256);
        #pragma unroll
        for (int j = 0; j < 8; ++j) {
          float pr = pl[rs32*16 + ii*8 + j];
          #pragma unroll
          for (int c = 0; c < 8; ++c) a[c] += pr * (float)vv[j][c];
        }
      }
    } else {
      const float* vbase = p.val + ((size_t)b*2048 + quarter*512 + rs32*16)*256 + l32*8;
      for (int ii = 0; ii < 4; ++ii) {
        float4 v4[4][2];
        #pragma unroll
        for (int j = 0; j < 4; ++j) {
          const float4* vp = (const float4*)(vbase + (size_t)(ii*4+j)*256);
          v4[j][0] = vp[0]; v4[j][1] = vp[1];
        }
        #pragma unroll
        for (int j = 0; j < 4; ++j) {
          float pr = pl[rs32*16 + ii*4 + j];
          a[0] += pr*v4[j][0].x; a[1] += pr*v4[j][0].y;
          a[2] += pr*v4[j][0].z; a[3] += pr*v4[j][0].w;
          a[4] += pr*v4[j][1].x; a[5] += pr*v4[j][1].y;
          a[6] += pr*v4[j][1].z; a[7] += pr*v4[j][1].w;
        }
      }
    }
    float* rd = red + rs32*256 + l32*8;
    ((float4*)rd)[0] = make_float4(a[0], a[1], a[2], a[3]);
    ((float4*)rd)[1] = make_float4(a[4], a[5], a[6], a[7]);
  }
  __syncthreads();
  if (tid < 256) {
    float s = 0;
    #pragma unroll
    for (int r = 0; r < 32; ++r) s += red[r*256 + tid];
    float* pb = p.parts + (size_t)b*1088 + quarter*272;
    pb[tid] = s;
    if (!tid) { pb[256] = scal[0]; pb[257] = scal[1]; }
  }
  __syncthreads();
  if (!tid) {
    __threadfence();
    __hip_atomic_fetch_add(p.qctr + (size_t)b*32, 1u, __ATOMIC_RELAXED, AGENT);
  }
  if (quarter == 0) {
    if (!tid) {
      while (__hip_atomic_load(p.qctr + (size_t)b*32, __ATOMIC_RELAXED, AGENT) < 4u*(unsigned)(t+1))
        __builtin_amdgcn_s_sleep(1);
      __threadfence();
    }
    __syncthreads();
    if (tid < 256) {
      const float* pb = p.parts + (size_t)b*1088;
      float m0 = pb[256], s0 = pb[257], m1 = pb[272+256], s1 = pb[272+257];
      float m2 = pb[544+256], s2 = pb[544+257], m3 = pb[816+256], s3 = pb[816+257];
      float M = fmaxf(fmaxf(m0, m1), fmaxf(m2, m3));
      float w0 = __expf(m0-M), w1 = __expf(m1-M), w2 = __expf(m2-M), w3 = __expf(m3-M);
      float S = w0*s0 + w1*s1 + w2*s2 + w3*s3;
      float cv = (w0*pb[tid] + w1*pb[272+tid] + w2*pb[544+tid] + w3*pb[816+tid]) / S;
      hbs[512 + tid] = (_Float16)cv;
      p.ctx[b*256 + tid] = (_Float16)cv;
    }
    __syncthreads();
    if (!tid) {   // publish ctx for next step's LSTM-A
      __threadfence();
      __hip_atomic_store(p.cflag + (size_t)b*32, t + 1, __ATOMIC_RELEASE, AGENT);
    }
    {
      int vq = tid >> 3, ks = tid & 7;
      if (vq < 34) {
        float a = 0;
        const h8* wr = (const h8*)(p.Wc + (size_t)vq*768 + ks*96);
        const h8* xx = (const h8*)hbs + ks*12;
        #pragma unroll
        for (int i = 0; i < 12; ++i) a = dot8(xx[i], wr[i], a);
        yred[vq*8 + ks] = a;
      }
    }
    __syncthreads();
    if (tid < 34) {
      float a = p.bc[tid];
      #pragma unroll
      for (int k = 0; k < 8; ++k) a += yred[tid*8 + k];
      p.out[((size_t)b*250 + t)*34 + tid] = a;
    }
  }
}

template<bool KV16>
__global__ __launch_bounds__(NT) void speller_main(P p) {
  __shared__ __align__(16) char sm[SMEM_BYTES];
  const int wg = blockIdx.x, tid = threadIdx.x;
  const int y64 = *p.flag;
  // precompute per-thread mask bits for energy phase (mask is step-invariant)
  unsigned mbits = 0;
  {
    const int b = wg >> 2, quarter = wg & 3;
    const int l = tid & 63, wv = tid >> 6, lr = l >> 4, lc = l & 15;
    if (lc == 0) {
      for (int it = 0; it < 8; ++it) {
        int rl = wv*32 + it*4 + lr;
        if (p.mask[b*2048 + quarter*512 + rl] > 0.f) mbits |= (1u << it);
      }
    }
  }
  int ep = 0;
  for (int t = 0; t < 250; ++t) {
    const int rd = t & 1, wr = 1 - rd;
    // wait for all 64 ctx values from step t-1 (replaces 3rd grid barrier)
    {
      for (;;) {
        int ok = 1;
        if (tid < 64) ok = (__hip_atomic_load(p.cflag + (size_t)tid*32, __ATOMIC_RELAXED, AGENT) >= t);
        if (__syncthreads_and(ok)) break;
      }
      if (!tid) __threadfence();
      __syncthreads();
    }
    lstm_phase<768, true>(sm, wg, tid, p.ctx, 256, p.ha + rd*32768, p.Wa,
                          p.Pemb, p.y, y64, t, p.ca, p.ha + wr*32768);
    gsync(p, ++ep);
    lstm_phase<1024, false>(sm, wg, tid, p.ha + wr*32768, 512, p.hb + rd*32768, p.Wb,
                            p.bb, nullptr, 0, 0, p.cb, p.hb + wr*32768);
    gsync(p, ++ep);
    attn<KV16>(sm, p, wg, tid, t, wr, mbits);
  }
}

__global__ void prep_a(P p, const float* emb, const float* Wih_a, const float* Whh_a,
    const float* bih_a, const float* bhh_a, const float* Wih_b, const float* Whh_b,
    const float* bih_b, const float* bhh_b, const float* Wqf, const float* Wcf,
    unsigned* zb, int* flag)
{
  int id = blockIdx.x*blockDim.x + threadIdx.x;
  int N = gridDim.x*blockDim.x;
  for (int i = id; i < (int)ZERO_W32; i += N) zb[i] = 0u;
  for (int i = id; i < 34*2048; i += N) {
    int v = i >> 11, n = i & 2047;
    float a = bih_a[n] + bhh_a[n];
    const float4* e4 = (const float4*)(emb + v*256);
    const float4* w4 = (const float4*)(Wih_a + (size_t)n*512);
    for (int k = 0; k < 64; ++k) {
      float4 x = e4[k], w = w4[k];
      a += x.x*w.x + x.y*w.y + x.z*w.z + x.w*w.w;
    }
    p.Pemb[i] = a;
  }
  for (int i = id; i < 2048*768; i += N) {
    int n = i / 768, k = i % 768;
    float w = (k < 256) ? Wih_a[(size_t)n*512 + 256 + k] : Whh_a[(size_t)n*512 + k - 256];
    p.Wa[i] = (_Float16)w;
  }
  for (int i = id; i < 2048*1024; i += N) {
    int n = i >> 10, k = i & 1023;
    float w = (k < 512) ? Wih_b[(size_t)n*512 + k] : Whh_b[(size_t)n*512 + k - 512];
    p.Wb[i] = (_Float16)w;
  }
  for (int i = id; i < 256*512; i += N) p.Wq[i] = (_Float16)Wqf[i];
  for (int i = id; i < 34*768; i += N) p.Wc[i] = (_Float16)Wcf[i];
  for (int i = id; i < 2048; i += N) p.bb[i] = bih_b[i] + bhh_b[i];
  if (id == 0) {
    const long long* yl = (const long long*)p.y;
    int ok = 1;
    for (int i = 0; i < 200; ++i) { long long v = yl[i]; if (v < 0 || v >= 34) { ok = 0; break; } }
    *flag = ok;
  }
}

__global__ void prep_kv(const float* key, const float* val, _Float16* k16, _Float16* v16) {
  int id = blockIdx.x*blockDim.x + threadIdx.x;
  int N = gridDim.x*blockDim.x;
  const int PER = 8388608; // float4 chunks per array
  for (int i = id; i < 2*PER; i += N) {
    const float4* src; _Float16* dst; int j;
    if (i < PER) { src = (const float4*)key; dst = k16; j = i; }
    else         { src = (const float4*)val; dst = v16; j = i - PER; }
    float4 x = src[j];
    h4 o; o[0] = (_Float16)x.x; o[1] = (_Float16)x.y; o[2] = (_Float16)x.z; o[3] = (_Float16)x.w;
    *(h4*)(dst + (size_t)j*4) = o;
  }
}

extern "C" void kernel_launch(void* const* d_in, const int* in_sizes, int n_in,
                              void* d_out, int out_size, void* d_ws, size_t ws_size,
                              hipStream_t stream) {
  char* ws = (char*)d_ws;
  P p;
  p.key = (const float*)d_in[0];
  p.val = (const float*)d_in[1];
  p.y   = d_in[2];
  p.mask = (const float*)d_in[3];
  p.bq = (const float*)d_in[14];
  p.bc = (const float*)d_in[16];
  p.grel = (int*)(ws + 128);
  p.ca = (float*)(ws + OFF_CA);
  p.cb = (float*)(ws + OFF_CB);
  p.ha = (_Float16*)(ws + OFF_HA);
  p.hb = (_Float16*)(ws + OFF_HB);
  p.ctx = (_Float16*)(ws + OFF_CTX);
  p.flags = (int*)(ws + OFF_FLAGS);
  p.cflag = (int*)(ws + OFF_CFLAG);
  p.qctr = (unsigned*)(ws + OFF_QCTR);
  p.parts = (float*)(ws + OFF_PART);
  p.Pemb = (float*)(ws + OFF_PEMB);
  p.bb = (float*)(ws + OFF_BB);
  p.flag = (const int*)(ws + OFF_FLAG);
  p.Wa = (_Float16*)(ws + OFF_WA);
  p.Wb = (_Float16*)(ws + OFF_WB);
  p.Wq = (_Float16*)(ws + OFF_WQ);
  p.Wc = (_Float16*)(ws + OFF_WC);
  p.k16 = (const _Float16*)(ws + OFF_K16);
  p.v16 = (const _Float16*)(ws + OFF_V16);
  p.out = (float*)d_out;

  bool kv16 = ws_size >= (size_t)TOTAL_FULL;

  prep_a<<<dim3(1024), dim3(256), 0, stream>>>(p,
      (const float*)d_in[4], (const float*)d_in[5], (const float*)d_in[6],
      (const float*)d_in[7], (const float*)d_in[8], (const float*)d_in[9],
      (const float*)d_in[10], (const float*)d_in[11], (const float*)d_in[12],
      (const float*)d_in[13], (const float*)d_in[15],
      (unsigned*)ws, (int*)(ws + OFF_FLAG));
  if (kv16) {
    prep_kv<<<dim3(4096), dim3(256), 0, stream>>>(p.key, p.val,
        (_Float16*)(ws + OFF_K16), (_Float16*)(ws + OFF_V16));
    speller_main<true><<<dim3(256), dim3(NT), 0, stream>>>(p);
  } else {
    speller_main<false><<<dim3(256), dim3(NT), 0, stream>>>(p);
  }
}